// Round 1
// baseline (1807.978 us; speedup 1.0000x reference)
//
#include <hip/hip_runtime.h>
#include <hip/hip_bf16.h>

// ---------------------------------------------------------------------------
// Generic fp32 GEMM with fused bias + activation epilogue.
// C[M,N] = act(A[M,K] @ W[N,K]^T + bias)
// MODE 0: val + b0[n] + b1[n]   (LSTM input projection: + bih + bhh)
// MODE 1: relu(val + b0[n])     (head layer 1)
// MODE 2: tanh(val + b0[n])     (head layer 2 / final output)
// Requires: BM==BN, BM*BK==1024 (one float4 load per thread per tile),
// 256 threads, M%BM==0, N%BN==0, K%BK==0.
// ---------------------------------------------------------------------------
template<int BM, int BN, int BK, int TM, int TN, int MODE>
__global__ __launch_bounds__(256) void gemm_bias_act(
    const float* __restrict__ A, const float* __restrict__ W,
    const float* __restrict__ b0, const float* __restrict__ b1,
    float* __restrict__ C, int M, int N, int K) {
  static_assert(BM == BN, "loader assumes square tile");
  static_assert(BM * BK == 1024, "one float4 per thread");
  __shared__ float As[BK][BM];
  __shared__ float Ws[BK][BN];
  const int tid = threadIdx.x;
  const int m0 = blockIdx.x * BM, n0 = blockIdx.y * BN;
  constexpr int KQ = BK / 4;
  const int lm = tid / KQ;
  const int lk = (tid % KQ) * 4;
  const int tx = tid % (BN / TN);
  const int ty = tid / (BN / TN);
  float acc[TM][TN] = {};

  for (int k0 = 0; k0 < K; k0 += BK) {
    float4 av = *reinterpret_cast<const float4*>(A + (size_t)(m0 + lm) * K + k0 + lk);
    float4 wv = *reinterpret_cast<const float4*>(W + (size_t)(n0 + lm) * K + k0 + lk);
    As[lk + 0][lm] = av.x; As[lk + 1][lm] = av.y; As[lk + 2][lm] = av.z; As[lk + 3][lm] = av.w;
    Ws[lk + 0][lm] = wv.x; Ws[lk + 1][lm] = wv.y; Ws[lk + 2][lm] = wv.z; Ws[lk + 3][lm] = wv.w;
    __syncthreads();
#pragma unroll
    for (int k = 0; k < BK; ++k) {
      float a[TM], b[TN];
#pragma unroll
      for (int i = 0; i < TM / 4; ++i)
        *reinterpret_cast<float4*>(&a[i * 4]) =
            *reinterpret_cast<const float4*>(&As[k][ty * TM + i * 4]);
#pragma unroll
      for (int i = 0; i < TN / 4; ++i)
        *reinterpret_cast<float4*>(&b[i * 4]) =
            *reinterpret_cast<const float4*>(&Ws[k][tx * TN + i * 4]);
#pragma unroll
      for (int i = 0; i < TM; ++i)
#pragma unroll
        for (int jj = 0; jj < TN; ++jj) acc[i][jj] += a[i] * b[jj];
    }
    __syncthreads();
  }

#pragma unroll
  for (int i = 0; i < TM; ++i) {
    const int m = m0 + ty * TM + i;
#pragma unroll
    for (int jq = 0; jq < TN / 4; ++jq) {
      float4 v;
      float* vp = &v.x;
#pragma unroll
      for (int u = 0; u < 4; ++u) {
        const int n = n0 + tx * TN + jq * 4 + u;
        float val = acc[i][jq * 4 + u];
        if (MODE == 0) {
          val += b0[n] + b1[n];
        } else if (MODE == 1) {
          val = fmaxf(val + b0[n], 0.f);
        } else {
          val = tanhf(val + b0[n]);
        }
        vp[u] = val;
      }
      *reinterpret_cast<float4*>(C + (size_t)m * N + n0 + tx * TN + jq * 4) = v;
    }
  }
}

// ---------------------------------------------------------------------------
// Sequential LSTM recurrence. One 512-thread block per (batch, direction).
// Thread j owns Whh row j (128 fp32 in VGPRs). h (128 floats) in LDS,
// broadcast-read each step. c held in registers of threads 0..127.
// xg is the precomputed input projection [B, T, 4H] (biases already added).
// Output written to out[b, t, dir*128 + j] (concat layout for next layer).
// ---------------------------------------------------------------------------
__global__ __launch_bounds__(512, 1) void lstm_seq(
    const float* __restrict__ xg_f, const float* __restrict__ xg_b,
    const float* __restrict__ Whh_f, const float* __restrict__ Whh_b,
    float* __restrict__ out) {
  const int b = blockIdx.x;
  const int dir = blockIdx.y;
  const int j = threadIdx.x;
  const float* __restrict__ xg = dir ? xg_b : xg_f;
  const float* __restrict__ Whh = dir ? Whh_b : Whh_f;

  __shared__ float4 h4[32];   // h state, 128 floats
  __shared__ float g_s[512];  // gate exchange

  float4 w[32];
#pragma unroll
  for (int k = 0; k < 32; ++k)
    w[k] = reinterpret_cast<const float4*>(Whh + (size_t)j * 128)[k];

  float c = 0.f;
  if (j < 32) h4[j] = make_float4(0.f, 0.f, 0.f, 0.f);
  __syncthreads();

  const int T = 512;
  const int tt0 = dir ? (T - 1) : 0;
  const int step = dir ? -1 : 1;
  const size_t base = (size_t)b * T * 512;

  float xg_next = xg[base + (size_t)tt0 * 512 + j];

  for (int t = 0; t < T; ++t) {
    const int tt = tt0 + step * t;
    float acc = xg_next;
    if (t + 1 < T) xg_next = xg[base + (size_t)(tt + step) * 512 + j];

    // g_j += dot(Whh row j, h)  -- 4 independent FMA chains
    float a0 = 0.f, a1 = 0.f, a2 = 0.f, a3 = 0.f;
#pragma unroll
    for (int k = 0; k < 32; ++k) {
      float4 hv = h4[k];
      a0 += w[k].x * hv.x;
      a1 += w[k].y * hv.y;
      a2 += w[k].z * hv.z;
      a3 += w[k].w * hv.w;
    }
    acc += (a0 + a1) + (a2 + a3);

    g_s[j] = acc;
    __syncthreads();  // g ready; everyone done reading h

    if (j < 128) {
      const float gi = 1.f / (1.f + __expf(-g_s[j]));
      const float gf = 1.f / (1.f + __expf(-g_s[j + 128]));
      const float gg = tanhf(g_s[j + 256]);
      const float go = 1.f / (1.f + __expf(-g_s[j + 384]));
      c = gf * c + gi * gg;
      const float h = go * tanhf(c);
      reinterpret_cast<float*>(h4)[j] = h;
      out[((size_t)b * T + tt) * 256 + dir * 128 + j] = h;
    }
    __syncthreads();  // h ready for next step
  }
}

// ---------------------------------------------------------------------------
// Launcher
// ---------------------------------------------------------------------------
extern "C" void kernel_launch(void* const* d_in, const int* in_sizes, int n_in,
                              void* d_out, int out_size, void* d_ws, size_t ws_size,
                              hipStream_t stream) {
  (void)in_sizes; (void)n_in; (void)out_size; (void)ws_size;

  const float* x     = (const float*)d_in[0];
  const float* Wih00 = (const float*)d_in[1];
  const float* Whh00 = (const float*)d_in[2];
  const float* bih00 = (const float*)d_in[3];
  const float* bhh00 = (const float*)d_in[4];
  const float* Wih01 = (const float*)d_in[5];
  const float* Whh01 = (const float*)d_in[6];
  const float* bih01 = (const float*)d_in[7];
  const float* bhh01 = (const float*)d_in[8];
  const float* Wih10 = (const float*)d_in[9];
  const float* Whh10 = (const float*)d_in[10];
  const float* bih10 = (const float*)d_in[11];
  const float* bhh10 = (const float*)d_in[12];
  const float* Wih11 = (const float*)d_in[13];
  const float* Whh11 = (const float*)d_in[14];
  const float* bih11 = (const float*)d_in[15];
  const float* bhh11 = (const float*)d_in[16];
  const float* W1 = (const float*)d_in[17];
  const float* b1 = (const float*)d_in[18];
  const float* W2 = (const float*)d_in[19];
  const float* b2 = (const float*)d_in[20];
  float* out = (float*)d_out;

  char* ws = (char*)d_ws;
  float* xg_fw = (float*)ws;                          // 64 MB  [B,T,512]
  float* xg_bw = (float*)(ws + ((size_t)64 << 20));   // 64 MB  [B,T,512]
  float* buf   = (float*)(ws + ((size_t)128 << 20));  // 32 MB  [B,T,256]
  // head intermediate reuses xg_fw (32 MB needed, 64 MB available)

  const int M = 64 * 512;  // 32768 rows

  // ---- layer 0 ----
  gemm_bias_act<128, 128, 8, 8, 8, 0><<<dim3(M / 128, 4), 256, 0, stream>>>(
      x, Wih00, bih00, bhh00, xg_fw, M, 512, 64);
  gemm_bias_act<128, 128, 8, 8, 8, 0><<<dim3(M / 128, 4), 256, 0, stream>>>(
      x, Wih01, bih01, bhh01, xg_bw, M, 512, 64);
  lstm_seq<<<dim3(64, 2), 512, 0, stream>>>(xg_fw, xg_bw, Whh00, Whh01, buf);

  // ---- layer 1 ----
  gemm_bias_act<128, 128, 8, 8, 8, 0><<<dim3(M / 128, 4), 256, 0, stream>>>(
      buf, Wih10, bih10, bhh10, xg_fw, M, 512, 256);
  gemm_bias_act<128, 128, 8, 8, 8, 0><<<dim3(M / 128, 4), 256, 0, stream>>>(
      buf, Wih11, bih11, bhh11, xg_bw, M, 512, 256);
  lstm_seq<<<dim3(64, 2), 512, 0, stream>>>(xg_fw, xg_bw, Whh10, Whh11, buf);

  // ---- head ----
  gemm_bias_act<128, 128, 8, 8, 8, 1><<<dim3(M / 128, 2), 256, 0, stream>>>(
      buf, W1, b1, nullptr, xg_fw, M, 256, 256);
  gemm_bias_act<64, 64, 16, 4, 4, 2><<<dim3(M / 64, 1), 256, 0, stream>>>(
      xg_fw, W2, b2, nullptr, out, M, 64, 256);
}

// Round 2
// 958.041 us; speedup vs baseline: 1.8872x; 1.8872x over previous
//
#include <hip/hip_runtime.h>
#include <hip/hip_bf16.h>
#include <hip/hip_fp16.h>

typedef _Float16 h2vec __attribute__((ext_vector_type(2)));

static __device__ __forceinline__ float fast_sigmoid(float x) {
  return __builtin_amdgcn_rcpf(1.f + __expf(-x));
}
static __device__ __forceinline__ float fast_tanh(float x) {
  // tanh(x) = 1 - 2/(exp(2x)+1); exp->v_exp, rcp->v_rcp. Large |x| saturates correctly.
  return 1.f - 2.f * __builtin_amdgcn_rcpf(__expf(2.f * x) + 1.f);
}
static __device__ __forceinline__ float fdot2u(unsigned int a, unsigned int b, float c) {
#if __has_builtin(__builtin_amdgcn_fdot2)
  return __builtin_amdgcn_fdot2(__builtin_bit_cast(h2vec, a),
                                __builtin_bit_cast(h2vec, b), c, false);
#else
  h2vec av = __builtin_bit_cast(h2vec, a);
  h2vec bv = __builtin_bit_cast(h2vec, b);
  return c + (float)av[0] * (float)bv[0] + (float)av[1] * (float)bv[1];
#endif
}
template<int CTRL>
static __device__ __forceinline__ float dpp_add(float v) {
  int x = __builtin_bit_cast(int, v);
  int y = __builtin_amdgcn_update_dpp(0, x, CTRL, 0xF, 0xF, true);
  return v + __builtin_bit_cast(float, y);
}

// ---------------------------------------------------------------------------
// Generic fp32 GEMM with fused bias + activation epilogue.
// C[M,N] = act(A[M,K] @ W[N,K]^T + bias)
// MODE 0: val + b0[n] + b1[n]; MODE 1: relu(val + b0[n]); MODE 2: tanh(val + b0[n])
// ---------------------------------------------------------------------------
template<int BM, int BN, int BK, int TM, int TN, int MODE>
__global__ __launch_bounds__(256) void gemm_bias_act(
    const float* __restrict__ A, const float* __restrict__ W,
    const float* __restrict__ b0, const float* __restrict__ b1,
    float* __restrict__ C, int M, int N, int K) {
  static_assert(BM == BN, "loader assumes square tile");
  static_assert(BM * BK == 1024, "one float4 per thread");
  __shared__ float As[BK][BM];
  __shared__ float Ws[BK][BN];
  const int tid = threadIdx.x;
  const int m0 = blockIdx.x * BM, n0 = blockIdx.y * BN;
  constexpr int KQ = BK / 4;
  const int lm = tid / KQ;
  const int lk = (tid % KQ) * 4;
  const int tx = tid % (BN / TN);
  const int ty = tid / (BN / TN);
  float acc[TM][TN] = {};

  for (int k0 = 0; k0 < K; k0 += BK) {
    float4 av = *reinterpret_cast<const float4*>(A + (size_t)(m0 + lm) * K + k0 + lk);
    float4 wv = *reinterpret_cast<const float4*>(W + (size_t)(n0 + lm) * K + k0 + lk);
    As[lk + 0][lm] = av.x; As[lk + 1][lm] = av.y; As[lk + 2][lm] = av.z; As[lk + 3][lm] = av.w;
    Ws[lk + 0][lm] = wv.x; Ws[lk + 1][lm] = wv.y; Ws[lk + 2][lm] = wv.z; Ws[lk + 3][lm] = wv.w;
    __syncthreads();
#pragma unroll
    for (int k = 0; k < BK; ++k) {
      float a[TM], b[TN];
#pragma unroll
      for (int i = 0; i < TM / 4; ++i)
        *reinterpret_cast<float4*>(&a[i * 4]) =
            *reinterpret_cast<const float4*>(&As[k][ty * TM + i * 4]);
#pragma unroll
      for (int i = 0; i < TN / 4; ++i)
        *reinterpret_cast<float4*>(&b[i * 4]) =
            *reinterpret_cast<const float4*>(&Ws[k][tx * TN + i * 4]);
#pragma unroll
      for (int i = 0; i < TM; ++i)
#pragma unroll
        for (int jj = 0; jj < TN; ++jj) acc[i][jj] += a[i] * b[jj];
    }
    __syncthreads();
  }

#pragma unroll
  for (int i = 0; i < TM; ++i) {
    const int m = m0 + ty * TM + i;
#pragma unroll
    for (int jq = 0; jq < TN / 4; ++jq) {
      float4 v;
      float* vp = &v.x;
#pragma unroll
      for (int u = 0; u < 4; ++u) {
        const int n = n0 + tx * TN + jq * 4 + u;
        float val = acc[i][jq * 4 + u];
        if (MODE == 0) {
          val += b0[n] + b1[n];
        } else if (MODE == 1) {
          val = fmaxf(val + b0[n], 0.f);
        } else {
          val = fast_tanh(val + b0[n]);
        }
        vp[u] = val;
      }
      *reinterpret_cast<float4*>(C + (size_t)m * N + n0 + tx * TN + jq * 4) = v;
    }
  }
}

// ---------------------------------------------------------------------------
// LSTM recurrence, v2. One 256-thread block per (batch, direction).
// Thread (j2 = tid>>2, kq = tid&3) computes 8 gate-rows {g*128 + 2*j2 + u}
// over k-quarter [kq*32, kq*32+32), weights as f16x2 in VGPRs (128 dwords).
// h kept in LDS as f16x2, 4 chunks padded to 20 dwords (bank-disjoint b128
// reads), double-buffered -> one barrier per step. Partial dots reduced
// across the 4 kq-lanes with DPP quad_perm butterfly (VALU-rate, no LDS).
// Dot product via v_dot2_f32_f16 (fp32 accumulate).
// ---------------------------------------------------------------------------
__global__ __launch_bounds__(256, 1) void lstm_seq2(
    const float* __restrict__ xg_f, const float* __restrict__ xg_b,
    const float* __restrict__ Whh_f, const float* __restrict__ Whh_b,
    float* __restrict__ out) {
  const int b = blockIdx.x;
  const int dir = blockIdx.y;
  const int tid = threadIdx.x;
  const int j2 = tid >> 2;  // 0..63 unit pair
  const int kq = tid & 3;   // k quarter
  const float* __restrict__ xg  = dir ? xg_b : xg_f;
  const float* __restrict__ Whh = dir ? Whh_b : Whh_f;

  __shared__ unsigned int hbuf[2][80];  // [buf][chunk*20 + dword], f16x2 h

  // Load + convert weights: w[g][u][kk] covers k = kq*32 + 2*kk .. +1
  unsigned int w[4][2][16];
#pragma unroll
  for (int g = 0; g < 4; ++g)
#pragma unroll
    for (int u = 0; u < 2; ++u) {
      const float4* wr = reinterpret_cast<const float4*>(
          Whh + (size_t)(g * 128 + 2 * j2 + u) * 128 + kq * 32);
#pragma unroll
      for (int q = 0; q < 8; ++q) {
        float4 v = wr[q];
        __half2 p0 = __floats2half2_rn(v.x, v.y);
        __half2 p1 = __floats2half2_rn(v.z, v.w);
        w[g][u][2 * q]     = __builtin_bit_cast(unsigned int, p0);
        w[g][u][2 * q + 1] = __builtin_bit_cast(unsigned int, p1);
      }
    }

  if (tid < 160) reinterpret_cast<unsigned int*>(hbuf)[tid] = 0u;
  float c0 = 0.f, c1 = 0.f;
  __syncthreads();

  const int tt0 = dir ? 511 : 0;
  const int stp = dir ? -1 : 1;
  const size_t base = (size_t)b * 512 * 512;
  const int xoff = kq * 128 + 2 * j2;
  const bool writer = (kq == (j2 >> 4));
  const int wdst = (j2 >> 4) * 20 + (j2 & 15);

  float2 xv = *reinterpret_cast<const float2*>(xg + base + (size_t)tt0 * 512 + xoff);

  for (int t = 0; t < 512; ++t) {
    const int tt = tt0 + stp * t;

    // read my h chunk (broadcast among 16 lanes, 4 bank-disjoint addresses)
    const unsigned int* hc = &hbuf[t & 1][kq * 20];
    uint4 q0 = reinterpret_cast<const uint4*>(hc)[0];
    uint4 q1 = reinterpret_cast<const uint4*>(hc)[1];
    uint4 q2 = reinterpret_cast<const uint4*>(hc)[2];
    uint4 q3 = reinterpret_cast<const uint4*>(hc)[3];
    unsigned int ha[16];
    ha[0] = q0.x; ha[1] = q0.y; ha[2] = q0.z; ha[3] = q0.w;
    ha[4] = q1.x; ha[5] = q1.y; ha[6] = q1.z; ha[7] = q1.w;
    ha[8] = q2.x; ha[9] = q2.y; ha[10] = q2.z; ha[11] = q2.w;
    ha[12] = q3.x; ha[13] = q3.y; ha[14] = q3.z; ha[15] = q3.w;

    // prefetch next step's xg (overlaps with dot2 chain)
    float2 xn = make_float2(0.f, 0.f);
    if (t + 1 < 512)
      xn = *reinterpret_cast<const float2*>(xg + base + (size_t)(tt + stp) * 512 + xoff);

    // accumulators; lane kq seeds gate g==kq with xg (added exactly once per row)
    float acc[4][2];
#pragma unroll
    for (int g = 0; g < 4; ++g) {
      acc[g][0] = (g == kq) ? xv.x : 0.f;
      acc[g][1] = (g == kq) ? xv.y : 0.f;
    }
#pragma unroll
    for (int kk = 0; kk < 16; ++kk) {
#pragma unroll
      for (int g = 0; g < 4; ++g) {
        acc[g][0] = fdot2u(w[g][0][kk], ha[kk], acc[g][0]);
        acc[g][1] = fdot2u(w[g][1][kk], ha[kk], acc[g][1]);
      }
    }
    // butterfly across the 4 kq lanes (quad): all lanes get identical sums
#pragma unroll
    for (int g = 0; g < 4; ++g)
#pragma unroll
      for (int u = 0; u < 2; ++u) {
        float a = acc[g][u];
        a = dpp_add<0xB1>(a);  // quad_perm [1,0,3,2]  (xor 1)
        a = dpp_add<0x4E>(a);  // quad_perm [2,3,0,1]  (xor 2)
        acc[g][u] = a;
      }

    const float i0 = fast_sigmoid(acc[0][0]), i1 = fast_sigmoid(acc[0][1]);
    const float f0 = fast_sigmoid(acc[1][0]), f1 = fast_sigmoid(acc[1][1]);
    const float g0 = fast_tanh(acc[2][0]),    g1 = fast_tanh(acc[2][1]);
    const float o0 = fast_sigmoid(acc[3][0]), o1 = fast_sigmoid(acc[3][1]);
    c0 = f0 * c0 + i0 * g0;
    c1 = f1 * c1 + i1 * g1;
    const float h0 = o0 * fast_tanh(c0);
    const float h1 = o1 * fast_tanh(c1);

    if (writer) {
      __half2 hp = __floats2half2_rn(h0, h1);
      hbuf[(t + 1) & 1][wdst] = __builtin_bit_cast(unsigned int, hp);
      *reinterpret_cast<float2*>(out + ((size_t)b * 512 + tt) * 256 + dir * 128 + 2 * j2)
          = make_float2(h0, h1);
    }
    xv = xn;
    __syncthreads();
  }
}

// ---------------------------------------------------------------------------
// Launcher
// ---------------------------------------------------------------------------
extern "C" void kernel_launch(void* const* d_in, const int* in_sizes, int n_in,
                              void* d_out, int out_size, void* d_ws, size_t ws_size,
                              hipStream_t stream) {
  (void)in_sizes; (void)n_in; (void)out_size; (void)ws_size;

  const float* x     = (const float*)d_in[0];
  const float* Wih00 = (const float*)d_in[1];
  const float* Whh00 = (const float*)d_in[2];
  const float* bih00 = (const float*)d_in[3];
  const float* bhh00 = (const float*)d_in[4];
  const float* Wih01 = (const float*)d_in[5];
  const float* Whh01 = (const float*)d_in[6];
  const float* bih01 = (const float*)d_in[7];
  const float* bhh01 = (const float*)d_in[8];
  const float* Wih10 = (const float*)d_in[9];
  const float* Whh10 = (const float*)d_in[10];
  const float* bih10 = (const float*)d_in[11];
  const float* bhh10 = (const float*)d_in[12];
  const float* Wih11 = (const float*)d_in[13];
  const float* Whh11 = (const float*)d_in[14];
  const float* bih11 = (const float*)d_in[15];
  const float* bhh11 = (const float*)d_in[16];
  const float* W1 = (const float*)d_in[17];
  const float* b1 = (const float*)d_in[18];
  const float* W2 = (const float*)d_in[19];
  const float* b2 = (const float*)d_in[20];
  float* out = (float*)d_out;

  char* ws = (char*)d_ws;
  float* xg_fw = (float*)ws;                          // 64 MB  [B,T,512]
  float* xg_bw = (float*)(ws + ((size_t)64 << 20));   // 64 MB  [B,T,512]
  float* buf   = (float*)(ws + ((size_t)128 << 20));  // 32 MB  [B,T,256]

  const int M = 64 * 512;  // 32768 rows

  // ---- layer 0 ----
  gemm_bias_act<128, 128, 8, 8, 8, 0><<<dim3(M / 128, 4), 256, 0, stream>>>(
      x, Wih00, bih00, bhh00, xg_fw, M, 512, 64);
  gemm_bias_act<128, 128, 8, 8, 8, 0><<<dim3(M / 128, 4), 256, 0, stream>>>(
      x, Wih01, bih01, bhh01, xg_bw, M, 512, 64);
  lstm_seq2<<<dim3(64, 2), 256, 0, stream>>>(xg_fw, xg_bw, Whh00, Whh01, buf);

  // ---- layer 1 ----
  gemm_bias_act<128, 128, 8, 8, 8, 0><<<dim3(M / 128, 4), 256, 0, stream>>>(
      buf, Wih10, bih10, bhh10, xg_fw, M, 512, 256);
  gemm_bias_act<128, 128, 8, 8, 8, 0><<<dim3(M / 128, 4), 256, 0, stream>>>(
      buf, Wih11, bih11, bhh11, xg_bw, M, 512, 256);
  lstm_seq2<<<dim3(64, 2), 256, 0, stream>>>(xg_fw, xg_bw, Whh10, Whh11, buf);

  // ---- head ----
  gemm_bias_act<128, 128, 8, 8, 8, 1><<<dim3(M / 128, 2), 256, 0, stream>>>(
      buf, W1, b1, nullptr, xg_fw, M, 256, 256);
  gemm_bias_act<64, 64, 16, 4, 4, 2><<<dim3(M / 64, 1), 256, 0, stream>>>(
      xg_fw, W2, b2, nullptr, out, M, 64, 256);
}